// Round 9
// baseline (121.165 us; speedup 1.0000x reference)
//
#include <hip/hip_runtime.h>
#include <hip/hip_fp16.h>

#define NN   2048
#define NF   512
#define MCH  10
#define QQ   64
#define KMAX 128          // max nnz per row of L_hat (expected ~32, max ~60)
#define TOL  2e-3f        // truncation budget (absmax threshold is 0.086)
#define PI_F 3.14159265358979323846f

__device__ inline float2 h2f2(unsigned u) { return __half22float2(*(__half2*)&u); }
__device__ inline unsigned f2h2(float a, float b) {
    __half2 h = __floats2half2_rn(a, b);
    return *(unsigned*)&h;
}

// ---------------------------------------------------------------------------
// Kernel A: transpose-cast x[r][f] (f32) -> xT[f][r] (f16) + per-block max|x|.
// grid (NN/64, NF/64) = (32, 8), block 256.  Both directions coalesced.
// ---------------------------------------------------------------------------
__global__ __launch_bounds__(256) void xpose_in(const float* __restrict__ x,
                                                unsigned short* __restrict__ xT,
                                                float* __restrict__ pmax) {
    __shared__ float tile[64][65];
    __shared__ float wm[4];
    int r0 = blockIdx.x * 64;
    int f0 = blockIdx.y * 64;
    int tx = threadIdx.x & 63, ty = threadIdx.x >> 6;
    float m = 0.f;
#pragma unroll
    for (int i = 0; i < 16; ++i) {
        int rr = ty * 16 + i;
        float v = x[(size_t)(r0 + rr) * NF + f0 + tx];
        tile[rr][tx] = v;
        m = fmaxf(m, fabsf(v));
    }
    __syncthreads();
#pragma unroll
    for (int i = 0; i < 16; ++i) {
        int ff = ty * 16 + i;
        __half h = __float2half_rn(tile[tx][ff]);
        xT[(size_t)(f0 + ff) * NN + r0 + tx] = __half_as_ushort(h);
    }
#pragma unroll
    for (int o = 32; o > 0; o >>= 1) m = fmaxf(m, __shfl_down(m, o));
    if ((threadIdx.x & 63) == 0) wm[threadIdx.x >> 6] = m;
    __syncthreads();
    if (threadIdx.x == 0)
        pmax[blockIdx.y * 32 + blockIdx.x] = fmaxf(fmaxf(wm[0], wm[1]), fmaxf(wm[2], wm[3]));
}

// ---------------------------------------------------------------------------
// Kernel B: e-major packed CSR of L_hat = (2/eig)*P - I.
//   packed[e*NN + row] = (col*16) << 16 | f16(val)
// High16 is the pre-scaled LDS byte offset (16 B per row: 4 replicated copies).
// Also writes the t passthrough output tail (one element per block).
// ---------------------------------------------------------------------------
__global__ __launch_bounds__(256) void csr_kernel(const float* __restrict__ P,
                                                  const float* __restrict__ eigmax,
                                                  const float* __restrict__ t,
                                                  unsigned* __restrict__ packed,
                                                  int* __restrict__ lens,
                                                  float* __restrict__ out) {
    int row = blockIdx.x;
    __shared__ int cnt;
    if (threadIdx.x == 0) cnt = 0;
    __syncthreads();
    float s2 = 2.0f / eigmax[0];
    for (int j = threadIdx.x; j < NN; j += 256) {
        float v = s2 * P[(size_t)row * NN + j] - (j == row ? 1.0f : 0.0f);
        if (v != 0.0f) {
            int p = atomicAdd(&cnt, 1);
            if (p < KMAX) {
                unsigned short hb = __half_as_ushort(__float2half_rn(v));
                packed[(size_t)p * NN + row] = ((unsigned)j << 20) | (unsigned)hb;
            }
        }
    }
    __syncthreads();
    if (threadIdx.x == 0) {
        lens[row] = min(cnt, KMAX);
        out[(size_t)NN * NF + row] = t[row];   // t passthrough (output tail)
    }
}

// ---------------------------------------------------------------------------
// Kernel C: fused coefficients + recurrence.  256 blocks x 1024 threads;
// block = 2-column slice; thread owns rows {tid, tid+1024}.
//  - Chebyshev coefficients computed in-block (cos table in LDS, __expf),
//    truncation order K block-locally (block spans all rows -> global K).
//  - Y slice as half2, 4-way replicated in LDS (16 B/row): lane reads copy
//    lane&3 (disjoint bank residues mod 4), rows written as one ds_write_b128.
//  - H accumulated in fp32 registers; coalesced I/O via xT/outT.
// ---------------------------------------------------------------------------
__global__ __launch_bounds__(1024) void cheb_fused(
    const unsigned short* __restrict__ xT, const float* __restrict__ t,
    const float* __restrict__ eigmax, const float* __restrict__ pmax,
    const unsigned* __restrict__ packed, const int* __restrict__ lens,
    float* __restrict__ outT) {
    __shared__ unsigned S[2][NN * 4];     // 64 KB: 4 replicated copies per row
    __shared__ float costab[QQ];
    __shared__ float redf[16];
    __shared__ int   redi[16];

    const int tid  = threadIdx.x;
    const int lane = tid & 63;
    const int wid  = tid >> 6;
    const int c0   = blockIdx.x * 2;
    const int r0   = tid;
    const int r1   = tid + 1024;

    if (tid < QQ) costab[tid] = cosf(PI_F * ((float)tid + 0.5f) / (float)QQ);

    // ---- global max|x| (for the truncation bound) ----
    float B = (tid < 256) ? pmax[tid] : 0.f;
#pragma unroll
    for (int o = 32; o > 0; o >>= 1) B = fmaxf(B, __shfl_down(B, o));
    if (lane == 0) redf[wid] = B;
    __syncthreads();
    B = redf[lane & 15];
#pragma unroll
    for (int o = 8; o > 0; o >>= 1) B = fmaxf(B, __shfl_down(B, o));
    B = __shfl(B, 0);
    const float bound = 45.2548f * B;   // sqrt(2048)*max|x| >= ||x[:,f]||_2 >= |Y_k|

    // ---- per-row Chebyshev coefficients (2 rows per thread) ----
    const float em = eigmax[0];
    const float sA = expf(t[r0]);
    const float sB = expf(t[r1]);
    float cA[MCH + 1], cB[MCH + 1];
#pragma unroll
    for (int k = 0; k <= MCH; ++k) { cA[k] = 0.f; cB[k] = 0.f; }
    for (int q = 0; q < QQ; ++q) {
        float ct = costab[q];
        float lam = em * 0.5f * (ct + 1.0f);
        float wA = __expf(-sA * lam);
        float wB = __expf(-sB * lam);
        float pmA = 1.f, pcA = ct, pmB = 1.f, pcB = ct;
        cA[0] += wA;          cB[0] += wB;
        cA[1] += wA * ct;     cB[1] += wB * ct;
#pragma unroll
        for (int k = 2; k <= MCH; ++k) {
            float nA = 2.f * ct * pcA - pmA;
            float nB = 2.f * ct * pcB - pmB;
            cA[k] += wA * nA;  cB[k] += wB * nB;
            pmA = pcA; pcA = nA;
            pmB = pcB; pcB = nB;
        }
    }
#pragma unroll
    for (int k = 0; k <= MCH; ++k) {
        float sc = 2.0f / (float)QQ;
        cA[k] *= sc; cB[k] *= sc;
    }
    cA[0] *= 0.5f; cB[0] *= 0.5f;

    // ---- adaptive truncation order K (block == global: block spans all rows)
    float tail0 = 0.f, tail1 = 0.f;
    int Ki = 1;
#pragma unroll
    for (int k = MCH; k >= 2; --k) {
        tail0 += fabsf(cA[k]);
        tail1 += fabsf(cB[k]);
        if (fmaxf(tail0, tail1) * bound > TOL) { Ki = k; break; }
    }
#pragma unroll
    for (int o = 32; o > 0; o >>= 1) Ki = max(Ki, __shfl_down(Ki, o));
    if (lane == 0) redi[wid] = Ki;
    __syncthreads();
    Ki = redi[lane & 15];
#pragma unroll
    for (int o = 8; o > 0; o >>= 1) Ki = max(Ki, __shfl_down(Ki, o));
    const int K = __shfl(Ki, 0);

    // ---- stage x slice (4 replicated copies per row, one b128 store) ----
    unsigned X0 = (unsigned)xT[(size_t)c0 * NN + r0] |
                  ((unsigned)xT[(size_t)(c0 + 1) * NN + r0] << 16);
    unsigned X1 = (unsigned)xT[(size_t)c0 * NN + r1] |
                  ((unsigned)xT[(size_t)(c0 + 1) * NN + r1] << 16);
    *(uint4*)&S[0][r0 * 4] = make_uint4(X0, X0, X0, X0);
    *(uint4*)&S[0][r1 * 4] = make_uint4(X1, X1, X1, X1);
    const int len0 = lens[r0];
    const int len1 = lens[r1];
    __syncthreads();

    const int laneoff = (tid & 3) * 4;   // this lane's replica (bank residue)
    auto gather = [&](int buf, int r, int len) -> unsigned {
        const char* Sb = (const char*)S[buf] + laneoff;
        unsigned accu = 0u;
        __half2 acc = *(__half2*)&accu;
#pragma unroll 8
        for (int e = 0; e < len; ++e) {
            unsigned pk = packed[(size_t)e * NN + r];            // coalesced dword
            unsigned g  = *(const unsigned*)(Sb + (pk >> 16));   // ds_read_b32
            unsigned v2 = __builtin_amdgcn_perm(pk, pk, 0x01000100u);  // dup val
            acc = __hfma2(*(__half2*)&v2, *(__half2*)&g, acc);   // v_pk_fma_f16
        }
        return *(unsigned*)&acc;
    };

    // Y1 = L_hat @ x ;  H = c0*x + c1*Y1
    unsigned A0 = gather(0, r0, len0);
    unsigned A1 = gather(0, r1, len1);
    *(uint4*)&S[1][r0 * 4] = make_uint4(A0, A0, A0, A0);
    *(uint4*)&S[1][r1 * 4] = make_uint4(A1, A1, A1, A1);
    float2 xf0 = h2f2(X0), xf1 = h2f2(X1);
    float2 yf0 = h2f2(A0), yf1 = h2f2(A1);
    float2 H0 = make_float2(cA[0] * xf0.x + cA[1] * yf0.x, cA[0] * xf0.y + cA[1] * yf0.y);
    float2 H1 = make_float2(cB[0] * xf1.x + cB[1] * yf1.x, cB[0] * xf1.y + cB[1] * yf1.y);

    int cur = 1;
#pragma unroll
    for (int k = 2; k <= MCH; ++k) {
        if (k > K) break;                 // block-uniform: safe with barriers
        __syncthreads();
        unsigned G0 = gather(cur, r0, len0);
        unsigned G1 = gather(cur, r1, len1);
        int oth = cur ^ 1;
        float2 gf0 = h2f2(G0), gf1 = h2f2(G1);
        float2 pf0 = h2f2(S[oth][r0 * 4]), pf1 = h2f2(S[oth][r1 * 4]);
        float2 t0 = make_float2(2.f * gf0.x - pf0.x, 2.f * gf0.y - pf0.y);
        float2 t1 = make_float2(2.f * gf1.x - pf1.x, 2.f * gf1.y - pf1.y);
        __syncthreads();   // all reads of S[oth] done before overwrite
        unsigned T0 = f2h2(t0.x, t0.y), T1 = f2h2(t1.x, t1.y);
        *(uint4*)&S[oth][r0 * 4] = make_uint4(T0, T0, T0, T0);
        *(uint4*)&S[oth][r1 * 4] = make_uint4(T1, T1, T1, T1);
        H0.x += cA[k] * t0.x; H0.y += cA[k] * t0.y;
        H1.x += cB[k] * t1.x; H1.y += cB[k] * t1.y;
        cur = oth;
    }

    outT[(size_t)c0 * NN + r0]       = H0.x;   // coalesced dword stores
    outT[(size_t)(c0 + 1) * NN + r0] = H0.y;
    outT[(size_t)c0 * NN + r1]       = H1.x;
    outT[(size_t)(c0 + 1) * NN + r1] = H1.y;
}

// ---------------------------------------------------------------------------
// Kernel D: transpose outT[f][r] -> out[r][f].  Both directions coalesced.
// ---------------------------------------------------------------------------
__global__ __launch_bounds__(256) void xpose_out(const float* __restrict__ outT,
                                                 float* __restrict__ out) {
    __shared__ float tile[64][65];
    int f0 = blockIdx.x * 64;
    int r0 = blockIdx.y * 64;
    int tx = threadIdx.x & 63, ty = threadIdx.x >> 6;
#pragma unroll
    for (int i = 0; i < 16; ++i) {
        int ff = ty * 16 + i;
        tile[ff][tx] = outT[(size_t)(f0 + ff) * NN + r0 + tx];
    }
    __syncthreads();
#pragma unroll
    for (int i = 0; i < 16; ++i) {
        int rr = ty * 16 + i;
        out[(size_t)(r0 + rr) * NF + f0 + tx] = tile[tx][rr];
    }
}

// ---------------------------------------------------------------------------
extern "C" void kernel_launch(void* const* d_in, const int* in_sizes, int n_in,
                              void* d_out, int out_size, void* d_ws, size_t ws_size,
                              hipStream_t stream) {
    const float* x      = (const float*)d_in[0];   // [N,F]
    const float* P_n    = (const float*)d_in[1];   // [N,N]
    const float* t      = (const float*)d_in[2];   // [N]
    const float* eigmax = (const float*)d_in[3];   // [1]
    float* out = (float*)d_out;

    char* p = (char*)d_ws;
    auto carve = [&](size_t bytes) -> void* {
        void* r = (void*)p;
        p += (bytes + 255) & ~(size_t)255;
        return r;
    };
    unsigned*       packed = (unsigned*)      carve((size_t)KMAX * NN * sizeof(unsigned));
    int*            lens   = (int*)           carve((size_t)NN * sizeof(int));
    float*          pmax   = (float*)         carve((size_t)256 * sizeof(float));
    unsigned short* xT     = (unsigned short*)carve((size_t)NF * NN * sizeof(unsigned short));
    float*          outT   = (float*)         carve((size_t)NF * NN * sizeof(float));

    xpose_in<<<dim3(NN / 64, NF / 64), dim3(256), 0, stream>>>(x, xT, pmax);
    csr_kernel<<<dim3(NN), dim3(256), 0, stream>>>(P_n, eigmax, t, packed, lens, out);
    cheb_fused<<<dim3(NF / 2), dim3(1024), 0, stream>>>(xT, t, eigmax, pmax,
                                                        packed, lens, outT);
    xpose_out<<<dim3(NF / 64, NN / 64), dim3(256), 0, stream>>>(outT, out);
}

// Round 10
// 107.561 us; speedup vs baseline: 1.1265x; 1.1265x over previous
//
#include <hip/hip_runtime.h>
#include <hip/hip_fp16.h>

#define NN   2048
#define NF   512
#define MCH  10
#define QQ   64
#define KMAX 128          // max nnz per row of L_hat (expected ~32, max ~60)
#define TOL  2e-3f        // truncation budget (absmax threshold is 0.086)
#define PI_F 3.14159265358979323846f

__device__ inline float2 h2f2(unsigned u) { return __half22float2(*(__half2*)&u); }
__device__ inline unsigned f2h2(float a, float b) {
    __half2 h = __floats2half2_rn(a, b);
    return *(unsigned*)&h;
}

// ---------------------------------------------------------------------------
// Kernel A: transpose-cast x[r][f] (f32) -> xT[f][r] (f16) + per-block max|x|.
// grid (NN/64, NF/64) = (32, 8), block 256.  Both directions coalesced.
// ---------------------------------------------------------------------------
__global__ __launch_bounds__(256) void xpose_in(const float* __restrict__ x,
                                                unsigned short* __restrict__ xT,
                                                float* __restrict__ pmax) {
    __shared__ float tile[64][65];
    __shared__ float wm[4];
    int r0 = blockIdx.x * 64;
    int f0 = blockIdx.y * 64;
    int tx = threadIdx.x & 63, ty = threadIdx.x >> 6;
    float m = 0.f;
#pragma unroll
    for (int i = 0; i < 16; ++i) {
        int rr = ty * 16 + i;
        float v = x[(size_t)(r0 + rr) * NF + f0 + tx];
        tile[rr][tx] = v;
        m = fmaxf(m, fabsf(v));
    }
    __syncthreads();
#pragma unroll
    for (int i = 0; i < 16; ++i) {
        int ff = ty * 16 + i;
        __half h = __float2half_rn(tile[tx][ff]);
        xT[(size_t)(f0 + ff) * NN + r0 + tx] = __half_as_ushort(h);
    }
#pragma unroll
    for (int o = 32; o > 0; o >>= 1) m = fmaxf(m, __shfl_down(m, o));
    if ((threadIdx.x & 63) == 0) wm[threadIdx.x >> 6] = m;
    __syncthreads();
    if (threadIdx.x == 0)
        pmax[blockIdx.y * 32 + blockIdx.x] = fmaxf(fmaxf(wm[0], wm[1]), fmaxf(wm[2], wm[3]));
}

// ---------------------------------------------------------------------------
// Kernel B: per-row CSR build + per-row Chebyshev coefficients.  2048 blocks,
// one row each.  CSR: threads scan the P row, compact nonzeros of
// L_hat = (2/eig)*P - I as packed[e*NN+row] = (col*4)<<16 | f16(val).
// Coeffs: lanes 0..63 take one quadrature point q each, butterfly-reduce the
// 11 cos(k*theta_q)-weighted terms in registers, lane 0 writes cc_cm[k][row].
// Also writes the t passthrough output tail.
// ---------------------------------------------------------------------------
__global__ __launch_bounds__(256) void csr_coeff(const float* __restrict__ P,
                                                 const float* __restrict__ eigmax,
                                                 const float* __restrict__ t,
                                                 unsigned* __restrict__ packed,
                                                 int* __restrict__ lens,
                                                 float* __restrict__ cc_cm,
                                                 float* __restrict__ out) {
    int row = blockIdx.x;
    __shared__ int cnt;
    if (threadIdx.x == 0) cnt = 0;
    __syncthreads();
    float em = eigmax[0];
    float s2 = 2.0f / em;
    for (int j = threadIdx.x; j < NN; j += 256) {
        float v = s2 * P[(size_t)row * NN + j] - (j == row ? 1.0f : 0.0f);
        if (v != 0.0f) {
            int p = atomicAdd(&cnt, 1);
            if (p < KMAX) {
                unsigned short hb = __half_as_ushort(__float2half_rn(v));
                packed[(size_t)p * NN + row] = ((unsigned)j << 18) | (unsigned)hb;
            }
        }
    }
    if (threadIdx.x < QQ) {          // first wave: one quadrature point per lane
        int q = threadIdx.x;
        float th = PI_F * ((float)q + 0.5f) / (float)QQ;
        float ct = cosf(th);
        float s  = expf(t[row]);
        float w  = __expf(-s * em * 0.5f * (ct + 1.0f));
        float tk[MCH + 1];
        tk[0] = w;
        tk[1] = w * ct;
        float pm = 1.f, pc = ct;
#pragma unroll
        for (int k = 2; k <= MCH; ++k) {
            float nx = 2.f * ct * pc - pm;
            tk[k] = w * nx;
            pm = pc; pc = nx;
        }
#pragma unroll
        for (int o = 32; o > 0; o >>= 1) {
#pragma unroll
            for (int k = 0; k <= MCH; ++k) tk[k] += __shfl_down(tk[k], o);
        }
        if (q == 0) {
#pragma unroll
            for (int k = 0; k <= MCH; ++k) {
                float v = tk[k] * (2.0f / (float)QQ);
                if (k == 0) v *= 0.5f;
                cc_cm[k * NN + row] = v;
            }
        }
    }
    __syncthreads();
    if (threadIdx.x == 0) {
        lens[row] = min(cnt, KMAX);
        out[(size_t)NN * NF + row] = t[row];   // t passthrough (output tail)
    }
}

// ---------------------------------------------------------------------------
// Kernel C: fused recurrence.  256 blocks x 1024 threads; block = 2-col slice;
// thread owns rows {tid, tid+1024}.  Plain half2 Y slice in LDS (16 KB);
// coefficients read from cc_cm (coalesced); adaptive K via block reduce of
// coefficient tails; coalesced I/O via xT / outT.
// ---------------------------------------------------------------------------
__global__ __launch_bounds__(1024) void cheb_fused(
    const unsigned short* __restrict__ xT, const float* __restrict__ pmax,
    const float* __restrict__ cc_cm,
    const unsigned* __restrict__ packed, const int* __restrict__ lens,
    float* __restrict__ outT) {
    __shared__ unsigned S[2][NN];
    __shared__ float redf[16];
    __shared__ int   redi[16];

    const int tid  = threadIdx.x;
    const int lane = tid & 63;
    const int wid  = tid >> 6;
    const int c0   = blockIdx.x * 2;
    const int r0   = tid;
    const int r1   = tid + 1024;

    // ---- coefficients for this thread's two rows (coalesced over tid) ----
    float cA[MCH + 1], cB[MCH + 1];
#pragma unroll
    for (int k = 0; k <= MCH; ++k) {
        cA[k] = cc_cm[k * NN + r0];
        cB[k] = cc_cm[k * NN + r1];
    }

    // ---- global max|x| -> truncation bound ----
    float B = (tid < 256) ? pmax[tid] : 0.f;
#pragma unroll
    for (int o = 32; o > 0; o >>= 1) B = fmaxf(B, __shfl_down(B, o));
    if (lane == 0) redf[wid] = B;
    __syncthreads();
    B = redf[lane & 15];
#pragma unroll
    for (int o = 8; o > 0; o >>= 1) B = fmaxf(B, __shfl_down(B, o));
    B = __shfl(B, 0);
    const float bound = 45.2548f * B;   // sqrt(2048)*max|x| >= ||x[:,f]||_2 >= |Y_k|

    // ---- adaptive truncation order K (block spans all rows -> global K) ----
    float tail0 = 0.f, tail1 = 0.f;
    int Ki = 1;
#pragma unroll
    for (int k = MCH; k >= 2; --k) {
        tail0 += fabsf(cA[k]);
        tail1 += fabsf(cB[k]);
        if (fmaxf(tail0, tail1) * bound > TOL) { Ki = k; break; }
    }
#pragma unroll
    for (int o = 32; o > 0; o >>= 1) Ki = max(Ki, __shfl_down(Ki, o));
    if (lane == 0) redi[wid] = Ki;
    __syncthreads();
    Ki = redi[lane & 15];
#pragma unroll
    for (int o = 8; o > 0; o >>= 1) Ki = max(Ki, __shfl_down(Ki, o));
    const int K = __shfl(Ki, 0);

    // ---- stage x slice ----
    unsigned X0 = (unsigned)xT[(size_t)c0 * NN + r0] |
                  ((unsigned)xT[(size_t)(c0 + 1) * NN + r0] << 16);
    unsigned X1 = (unsigned)xT[(size_t)c0 * NN + r1] |
                  ((unsigned)xT[(size_t)(c0 + 1) * NN + r1] << 16);
    S[0][r0] = X0;
    S[0][r1] = X1;
    const int len0 = lens[r0];
    const int len1 = lens[r1];
    __syncthreads();

    auto gather = [&](int buf, int r, int len) -> unsigned {
        const char* Sb = (const char*)S[buf];
        unsigned accu = 0u;
        __half2 acc = *(__half2*)&accu;
#pragma unroll 8
        for (int e = 0; e < len; ++e) {
            unsigned pk = packed[(size_t)e * NN + r];            // coalesced dword
            unsigned g  = *(const unsigned*)(Sb + (pk >> 16));   // ds_read_b32
            unsigned v2 = __builtin_amdgcn_perm(pk, pk, 0x01000100u);  // dup val
            acc = __hfma2(*(__half2*)&v2, *(__half2*)&g, acc);   // v_pk_fma_f16
        }
        return *(unsigned*)&acc;
    };

    // Y1 = L_hat @ x ;  H = c0*x + c1*Y1
    unsigned A0 = gather(0, r0, len0);
    unsigned A1 = gather(0, r1, len1);
    S[1][r0] = A0;
    S[1][r1] = A1;
    float2 xf0 = h2f2(X0), xf1 = h2f2(X1);
    float2 yf0 = h2f2(A0), yf1 = h2f2(A1);
    float2 H0 = make_float2(cA[0] * xf0.x + cA[1] * yf0.x, cA[0] * xf0.y + cA[1] * yf0.y);
    float2 H1 = make_float2(cB[0] * xf1.x + cB[1] * yf1.x, cB[0] * xf1.y + cB[1] * yf1.y);

    int cur = 1;
#pragma unroll
    for (int k = 2; k <= MCH; ++k) {
        if (k > K) break;                 // block-uniform: safe with barriers
        __syncthreads();
        unsigned G0 = gather(cur, r0, len0);
        unsigned G1 = gather(cur, r1, len1);
        int oth = cur ^ 1;
        float2 gf0 = h2f2(G0), gf1 = h2f2(G1);
        float2 pf0 = h2f2(S[oth][r0]), pf1 = h2f2(S[oth][r1]);
        float2 t0 = make_float2(2.f * gf0.x - pf0.x, 2.f * gf0.y - pf0.y);
        float2 t1 = make_float2(2.f * gf1.x - pf1.x, 2.f * gf1.y - pf1.y);
        __syncthreads();   // all reads of S[oth] done before overwrite
        S[oth][r0] = f2h2(t0.x, t0.y);
        S[oth][r1] = f2h2(t1.x, t1.y);
        H0.x += cA[k] * t0.x; H0.y += cA[k] * t0.y;
        H1.x += cB[k] * t1.x; H1.y += cB[k] * t1.y;
        cur = oth;
    }

    outT[(size_t)c0 * NN + r0]       = H0.x;   // coalesced dword stores
    outT[(size_t)(c0 + 1) * NN + r0] = H0.y;
    outT[(size_t)c0 * NN + r1]       = H1.x;
    outT[(size_t)(c0 + 1) * NN + r1] = H1.y;
}

// ---------------------------------------------------------------------------
// Kernel D: transpose outT[f][r] -> out[r][f].  Both directions coalesced.
// ---------------------------------------------------------------------------
__global__ __launch_bounds__(256) void xpose_out(const float* __restrict__ outT,
                                                 float* __restrict__ out) {
    __shared__ float tile[64][65];
    int f0 = blockIdx.x * 64;
    int r0 = blockIdx.y * 64;
    int tx = threadIdx.x & 63, ty = threadIdx.x >> 6;
#pragma unroll
    for (int i = 0; i < 16; ++i) {
        int ff = ty * 16 + i;
        tile[ff][tx] = outT[(size_t)(f0 + ff) * NN + r0 + tx];
    }
    __syncthreads();
#pragma unroll
    for (int i = 0; i < 16; ++i) {
        int rr = ty * 16 + i;
        out[(size_t)(r0 + rr) * NF + f0 + tx] = tile[tx][rr];
    }
}

// ---------------------------------------------------------------------------
extern "C" void kernel_launch(void* const* d_in, const int* in_sizes, int n_in,
                              void* d_out, int out_size, void* d_ws, size_t ws_size,
                              hipStream_t stream) {
    const float* x      = (const float*)d_in[0];   // [N,F]
    const float* P_n    = (const float*)d_in[1];   // [N,N]
    const float* t      = (const float*)d_in[2];   // [N]
    const float* eigmax = (const float*)d_in[3];   // [1]
    float* out = (float*)d_out;

    char* p = (char*)d_ws;
    auto carve = [&](size_t bytes) -> void* {
        void* r = (void*)p;
        p += (bytes + 255) & ~(size_t)255;
        return r;
    };
    unsigned*       packed = (unsigned*)      carve((size_t)KMAX * NN * sizeof(unsigned));
    int*            lens   = (int*)           carve((size_t)NN * sizeof(int));
    float*          cc_cm  = (float*)         carve((size_t)(MCH + 1) * NN * sizeof(float));
    float*          pmax   = (float*)         carve((size_t)256 * sizeof(float));
    unsigned short* xT     = (unsigned short*)carve((size_t)NF * NN * sizeof(unsigned short));
    float*          outT   = (float*)         carve((size_t)NF * NN * sizeof(float));

    xpose_in<<<dim3(NN / 64, NF / 64), dim3(256), 0, stream>>>(x, xT, pmax);
    csr_coeff<<<dim3(NN), dim3(256), 0, stream>>>(P_n, eigmax, t, packed, lens, cc_cm, out);
    cheb_fused<<<dim3(NF / 2), dim3(1024), 0, stream>>>(xT, pmax, cc_cm, packed, lens, outT);
    xpose_out<<<dim3(NF / 64, NN / 64), dim3(256), 0, stream>>>(outT, out);
}